// Round 7
// baseline (459.058 us; speedup 1.0000x reference)
//
#include <hip/hip_runtime.h>
#include <hip/hip_bf16.h>
#include <math.h>

#define H 768
#define B 256
#define T 100

typedef __attribute__((ext_vector_type(8))) short short8;
typedef __attribute__((ext_vector_type(4))) float f32x4;
typedef __attribute__((ext_vector_type(4))) unsigned short us4;
typedef unsigned long long u64;

static __device__ __forceinline__ float sigm(float x) {
    return 1.0f / (1.0f + __expf(-x));
}
static __device__ __forceinline__ float tanh_fast(float x) {
    return 1.0f - 2.0f / (__expf(2.0f * x) + 1.0f);
}
static __device__ __forceinline__ unsigned short bf16b(float x) {
    __hip_bfloat16 h = __float2bfloat16(x);
    return *(unsigned short*)&h;
}

// ---------------- fused prep, R19 vectorized (single dispatch) ----------------
//   bid <  2400 : sig zero   (block: 16KB via 4 x 16B stores/thread)
//   bid <  5472 : weight row y=bid-2400 (tid<192: float4 x2 loads,
//                 us4 stores to Wc + Wcat; tid==0: bias)
//   bid <  5552 : Wp row r=bid-5472 (zero-padded beyond 72)
//   bid <  5808 : A0 batch row b=bid-5552  [x0|h0]
__global__ __launch_bounds__(256) void prep_all(
        const float* __restrict__ src, const float* __restrict__ h0,
        const float* __restrict__ Wih, const float* __restrict__ Whh,
        const float* __restrict__ bih, const float* __restrict__ bhh,
        const float* __restrict__ Wpost,
        __hip_bfloat16* __restrict__ Wc,    // 3072 x 768 (Wih+Whh)
        __hip_bfloat16* __restrict__ Wcat,  // 3072 x 1536 [Wih|Whh]
        float* __restrict__ bias,           // 3072
        __hip_bfloat16* __restrict__ Wp,    // 80 x 768
        __hip_bfloat16* __restrict__ A0,    // 256 x 1536 [x0|h0]
        u64* __restrict__ sig64)            // T*B*192 u64, zeroed
{
    const int bid = blockIdx.x;
    const int tid = threadIdx.x;

    if (bid < 2400) {
        char* bz = (char*)sig64 + (size_t)bid * 16384;
        const f32x4 z = {0.f, 0.f, 0.f, 0.f};
#pragma unroll
        for (int jj = 0; jj < 4; ++jj)
            *(f32x4*)(bz + (size_t)jj * 4096 + (size_t)tid * 16) = z;
    } else if (bid < 5472) {
        const int y = bid - 2400;
        if (tid < 192) {
            const int k4 = tid * 4;
            f32x4 a = *(const f32x4*)(Wih + (size_t)y * H + k4);
            f32x4 b = *(const f32x4*)(Whh + (size_t)y * H + k4);
            us4 wc, wa, wb;
#pragma unroll
            for (int i = 0; i < 4; ++i) {
                wc[i] = bf16b(a[i] + b[i]);
                wa[i] = bf16b(a[i]);
                wb[i] = bf16b(b[i]);
            }
            unsigned short* WcS   = (unsigned short*)Wc;
            unsigned short* WcatS = (unsigned short*)Wcat;
            *(us4*)(WcS   + (size_t)y * 768  + k4)       = wc;
            *(us4*)(WcatS + (size_t)y * 1536 + k4)       = wa;
            *(us4*)(WcatS + (size_t)y * 1536 + 768 + k4) = wb;
        }
        if (tid == 0) bias[y] = bih[y] + bhh[y];
    } else if (bid < 5552) {
        const int r = bid - 5472;
        if (tid < 192) {
            const int k4 = tid * 4;
            us4 w = {0, 0, 0, 0};
            if (r < 72) {
                f32x4 v = *(const f32x4*)(Wpost + (size_t)r * H + k4);
#pragma unroll
                for (int i = 0; i < 4; ++i) w[i] = bf16b(v[i]);
            }
            *(us4*)((unsigned short*)Wp + (size_t)r * 768 + k4) = w;
        }
    } else {
        const int b = bid - 5552;
        if (tid < 192) {
            const int k4 = tid * 4;
            f32x4 s = *(const f32x4*)(src + ((size_t)b * 16 + 15) * H + k4);
            f32x4 h = *(const f32x4*)(h0  + (size_t)b * H + k4);
            us4 ws, wh;
#pragma unroll
            for (int i = 0; i < 4; ++i) { ws[i] = bf16b(s[i]); wh[i] = bf16b(h[i]); }
            unsigned short* A0S = (unsigned short*)A0;
            *(us4*)(A0S + (size_t)b * 1536 + k4)       = ws;
            *(us4*)(A0S + (size_t)b * 1536 + 768 + k4) = wh;
        }
    }
}

// ---------------- persistent recurrence: steps 0..99 ----------------
// R14 skeleton (proven 354us). Exchange protocol UNTOUCHED (R15-R18 lessons:
// MALL is the only cross-block rendezvous; poll-is-the-load wins; per-step
// release fences are catastrophic; folding proj regresses).
// R22 serial-path cuts:
//  (1) (D) barrier is now a BARE s_barrier (no vmcnt(0) drain). The publish
//      store drain (~400-600cy) now overlaps the next step's poll sweeps
//      instead of sitting serially in the step. Correctness: cross-block
//      visibility is enforced by sig_ok polling (waits as long as needed);
//      intra-block LDS ordering is covered by (B)/(C) which stay full
//      __syncthreads; xch and lds_h are distinct buffers.
//  (2) K=768 GEMM uses dual accumulators (even/odd KSTEP -> acc0/acc1),
//      halving the 24-deep dependent-MFMA latency chain. fp32 sum order
//      changes (absmax headroom 3.5x).
#define LDS_H_STRIDE  772    // shorts; 8B-aligned rows, low conflicts (R9-measured)
#define LDS_T0_STRIDE 1540   // shorts
#define XCH_STRIDE    17     // 16 + 1 pad floats

#define LDW8(n0,n1,n2,n3,n4,n5,n6,n7, p) \
    asm volatile("global_load_dwordx4 %0, %8, off\n\t" \
                 "global_load_dwordx4 %1, %8, off offset:64\n\t" \
                 "global_load_dwordx4 %2, %8, off offset:128\n\t" \
                 "global_load_dwordx4 %3, %8, off offset:192\n\t" \
                 "global_load_dwordx4 %4, %8, off offset:256\n\t" \
                 "global_load_dwordx4 %5, %8, off offset:320\n\t" \
                 "global_load_dwordx4 %6, %8, off offset:384\n\t" \
                 "global_load_dwordx4 %7, %8, off offset:448\n\t" \
                 "s_waitcnt vmcnt(0)" \
                 : "=&v"(n0),"=&v"(n1),"=&v"(n2),"=&v"(n3), \
                   "=&v"(n4),"=&v"(n5),"=&v"(n6),"=&v"(n7) \
                 : "v"(p))

#define KSTEP(ac, nm, idx) { \
    short8 a_ = *(const short8*)(&lds_h[col * LDS_H_STRIDE + (idx) * 32 + quad * 8]); \
    ac = __builtin_amdgcn_mfma_f32_16x16x32_bf16(a_, nm, ac, 0, 0, 0); }

static __device__ __forceinline__ bool sig_ok(u64 x) {
    return (unsigned short)x && (unsigned short)(x >> 16) &&
           (unsigned short)(x >> 32) && (unsigned short)(x >> 48);
}

__global__ __launch_bounds__(768, 3) void lstm_persist(
    const __hip_bfloat16* __restrict__ Wc,    // 3072 x 768 bf16 (Wih+Whh)
    const __hip_bfloat16* __restrict__ Wcat,  // 3072 x 1536 bf16 [Wih|Whh]
    const float* __restrict__ bias,           // 3072
    const float* __restrict__ c0in,           // B x H fp32
    const __hip_bfloat16* __restrict__ A0,    // 256 x 1536 [x0|h0]
    unsigned* sig)                            // T x B x 384 u32 (~bf16 pairs), zeroed
{
    const int mtg  = blockIdx.x >> 4;    // batch group 0..15 (16 batches)
    const int jg   = blockIdx.x & 15;    // j group 0..15 (48 j values)
    const int tid  = threadIdx.x;
    const int lane = tid & 63;
    const int wave = tid >> 6;           // 0..11
    const int col  = lane & 15;
    const int quad = lane >> 4;
    const int jt_l = wave >> 2;          // 0..2  local j-tile
    const int gate = wave & 3;           // 0..3  (i,f,g,o)
    const int j    = jg * 48 + jt_l * 16 + col;   // this wave's j column

    __shared__ short lds_h[16 * LDS_T0_STRIDE];   // 49280 B (t0 tile; t>=1 stride 772)
    __shared__ float xch[12 * 16 * XCH_STRIDE];   // 13056 B gate exchange

    // ---- pin resident weight slice (Wc) in regs: 24 x short8 (sound asm) ----
    const short* wptr = (const short*)Wc + (size_t)(gate * H + j) * H + quad * 8;
    short8 w00,w01,w02,w03,w04,w05,w06,w07,w08,w09,w10,w11,
           w12,w13,w14,w15,w16,w17,w18,w19,w20,w21,w22,w23;
    LDW8(w00,w01,w02,w03,w04,w05,w06,w07, wptr);
    LDW8(w08,w09,w10,w11,w12,w13,w14,w15, wptr + 256);
    LDW8(w16,w17,w18,w19,w20,w21,w22,w23, wptr + 512);

    // ---- cell-role state (threads 0..383: two adjacent-j cells each) ----
    const int p    = tid;                 // pair id if < 384 (waves 0..5)
    const int bb   = p / 24;              // local batch 0..15
    const int jp   = p % 24;
    const int jloc = jp * 2;              // local j 0..46 (even)
    const int cjt  = jloc >> 4;           // j-tile of the pair
    const int jcol = jloc & 15;
    const int bglob = mtg * 16 + bb;
    const int jglob = jg * 48 + jloc;
    float c0v = 0.f, c1v = 0.f;
    float bi0=0,bi1=0,bf0=0,bf1=0,bg0=0,bg1=0,bo0=0,bo1=0;
    if (p < 384) {
        c0v = c0in[(size_t)bglob * H + jglob];
        c1v = c0in[(size_t)bglob * H + jglob + 1];
        bi0 = bias[0*H + jglob]; bi1 = bias[0*H + jglob + 1];
        bf0 = bias[1*H + jglob]; bf1 = bias[1*H + jglob + 1];
        bg0 = bias[2*H + jglob]; bg1 = bias[2*H + jglob + 1];
        bo0 = bias[3*H + jglob]; bo1 = bias[3*H + jglob + 1];
    }

    const u64* sig64c = (const u64*)sig;
    const int r0  = tid / 192;    // staging row base 0..3
    const int wrd = tid % 192;    // u64 word within row

    for (int t = 0; t < T; ++t) {
        f32x4 acc0 = {0.f, 0.f, 0.f, 0.f};
        f32x4 acc1 = {0.f, 0.f, 0.f, 0.f};

        if (t == 0) {
            // ---- stage A0[16 rows][1536] -> LDS (plain loads) ----
            const u64* a8 = (const u64*)((const short*)A0 + (size_t)(mtg * 16) * 1536);
#pragma unroll
            for (int i = 0; i < 8; ++i) {
                int idx = tid + i * 768;      // 0..6143 (16 rows x 384 u64)
                int br  = idx / 384;
                int ch  = idx % 384;
                *(u64*)&lds_h[br * LDS_T0_STRIDE + ch * 4] = a8[(size_t)br * 384 + ch];
            }
            __syncthreads();   // (B)

            // ---- K=1536 GEMM streaming Wcat (one-time) ----
            const short* wq = (const short*)Wcat + (size_t)(gate * H + j) * 1536 + quad * 8;
            for (int kk = 0; kk < 48; ++kk) {
                short8 a_ = *(const short8*)(&lds_h[col * LDS_T0_STRIDE + kk * 32 + quad * 8]);
                short8 b_ = *(const short8*)(wq + kk * 32);
                acc0 = __builtin_amdgcn_mfma_f32_16x16x32_bf16(a_, b_, acc0, 0, 0, 0);
            }
        } else {
            // ---- poll+stage h(t-1): 4 owned u64 words, BATCHED loads ----
            const u64* hb = sig64c + ((size_t)(t - 1) * B + (size_t)(mtg * 16)) * 192 + wrd;
            u64 x0 = __hip_atomic_load(hb + (size_t)(r0     ) * 192,
                                       __ATOMIC_RELAXED, __HIP_MEMORY_SCOPE_AGENT);
            u64 x1 = __hip_atomic_load(hb + (size_t)(r0 +  4) * 192,
                                       __ATOMIC_RELAXED, __HIP_MEMORY_SCOPE_AGENT);
            u64 x2 = __hip_atomic_load(hb + (size_t)(r0 +  8) * 192,
                                       __ATOMIC_RELAXED, __HIP_MEMORY_SCOPE_AGENT);
            u64 x3 = __hip_atomic_load(hb + (size_t)(r0 + 12) * 192,
                                       __ATOMIC_RELAXED, __HIP_MEMORY_SCOPE_AGENT);
            unsigned pending = 0xFu;
            if (sig_ok(x0)) { *(u64*)&lds_h[(r0     ) * LDS_H_STRIDE + wrd * 4] = ~x0; pending &= ~1u; }
            if (sig_ok(x1)) { *(u64*)&lds_h[(r0 +  4) * LDS_H_STRIDE + wrd * 4] = ~x1; pending &= ~2u; }
            if (sig_ok(x2)) { *(u64*)&lds_h[(r0 +  8) * LDS_H_STRIDE + wrd * 4] = ~x2; pending &= ~4u; }
            if (sig_ok(x3)) { *(u64*)&lds_h[(r0 + 12) * LDS_H_STRIDE + wrd * 4] = ~x3; pending &= ~8u; }
            int guard = 0;
            while (pending && ++guard < (1 << 22)) {
                __builtin_amdgcn_s_sleep(4);   // throttle: ~256 cyc between sweeps
                if (pending & 1u) x0 = __hip_atomic_load(hb + (size_t)(r0     ) * 192,
                                        __ATOMIC_RELAXED, __HIP_MEMORY_SCOPE_AGENT);
                if (pending & 2u) x1 = __hip_atomic_load(hb + (size_t)(r0 +  4) * 192,
                                        __ATOMIC_RELAXED, __HIP_MEMORY_SCOPE_AGENT);
                if (pending & 4u) x2 = __hip_atomic_load(hb + (size_t)(r0 +  8) * 192,
                                        __ATOMIC_RELAXED, __HIP_MEMORY_SCOPE_AGENT);
                if (pending & 8u) x3 = __hip_atomic_load(hb + (size_t)(r0 + 12) * 192,
                                        __ATOMIC_RELAXED, __HIP_MEMORY_SCOPE_AGENT);
                if ((pending & 1u) && sig_ok(x0)) { *(u64*)&lds_h[(r0     ) * LDS_H_STRIDE + wrd * 4] = ~x0; pending &= ~1u; }
                if ((pending & 2u) && sig_ok(x1)) { *(u64*)&lds_h[(r0 +  4) * LDS_H_STRIDE + wrd * 4] = ~x1; pending &= ~2u; }
                if ((pending & 4u) && sig_ok(x2)) { *(u64*)&lds_h[(r0 +  8) * LDS_H_STRIDE + wrd * 4] = ~x2; pending &= ~4u; }
                if ((pending & 8u) && sig_ok(x3)) { *(u64*)&lds_h[(r0 + 12) * LDS_H_STRIDE + wrd * 4] = ~x3; pending &= ~8u; }
            }
            __syncthreads();   // (B) lds_h ready

            // ---- K=768 GEMM vs pinned weights (dual acc chains) ----
            KSTEP(acc0,w00,0)  KSTEP(acc1,w01,1)  KSTEP(acc0,w02,2)  KSTEP(acc1,w03,3)
            KSTEP(acc0,w04,4)  KSTEP(acc1,w05,5)  KSTEP(acc0,w06,6)  KSTEP(acc1,w07,7)
            KSTEP(acc0,w08,8)  KSTEP(acc1,w09,9)  KSTEP(acc0,w10,10) KSTEP(acc1,w11,11)
            KSTEP(acc0,w12,12) KSTEP(acc1,w13,13) KSTEP(acc0,w14,14) KSTEP(acc1,w15,15)
            KSTEP(acc0,w16,16) KSTEP(acc1,w17,17) KSTEP(acc0,w18,18) KSTEP(acc1,w19,19)
            KSTEP(acc0,w20,20) KSTEP(acc1,w21,21) KSTEP(acc0,w22,22) KSTEP(acc1,w23,23)
        }

        // ---- exchange gate tiles through LDS ----
        f32x4 acc = acc0 + acc1;
        float* xw = &xch[(size_t)wave * 16 * XCH_STRIDE];
#pragma unroll
        for (int r = 0; r < 4; ++r)
            xw[(quad * 4 + r) * XCH_STRIDE + col] = acc[r];
        __syncthreads();   // (C) xch ready; all lds_h reads of this step done

        // ---- cell update + inverted-bf16 publish (store IS the signal) ----
        if (p < 384) {
            const float* xg = &xch[(size_t)(cjt * 4) * 16 * XCH_STRIDE + bb * XCH_STRIDE + jcol];
            const int gs = 16 * XCH_STRIDE;
            float i0 = xg[0*gs] + bi0, i1 = xg[0*gs + 1] + bi1;
            float f0 = xg[1*gs] + bf0, f1 = xg[1*gs + 1] + bf1;
            float g0 = xg[2*gs] + bg0, g1 = xg[2*gs + 1] + bg1;
            float o0 = xg[3*gs] + bo0, o1 = xg[3*gs + 1] + bo1;
            float cn0 = sigm(f0) * c0v + sigm(i0) * tanh_fast(g0);
            float cn1 = sigm(f1) * c1v + sigm(i1) * tanh_fast(g1);
            c0v = cn0; c1v = cn1;
            __hip_bfloat16 h0b = __float2bfloat16(sigm(o0) * tanh_fast(cn0));
            __hip_bfloat16 h1b = __float2bfloat16(sigm(o1) * tanh_fast(cn1));
            unsigned lo = (unsigned)(unsigned short)~(*(unsigned short*)&h0b);  // nonzero
            unsigned hi = (unsigned)(unsigned short)~(*(unsigned short*)&h1b);  // nonzero
            __hip_atomic_store(&sig[((size_t)t * B + bglob) * 384 + (jglob >> 1)],
                               lo | (hi << 16),
                               __ATOMIC_RELAXED, __HIP_MEMORY_SCOPE_AGENT);
        }
        // (D) poll-throttle barrier WITHOUT store drain: publishes flow to the
        // MALL while the next step's first poll sweeps issue. sig_ok polling
        // provides the only cross-block ordering needed.
        asm volatile("s_barrier" ::: "memory");
    }
}

// ---------------- post projection (reads inverted sig) ----------------
__global__ __launch_bounds__(64) void proj(
    const short* __restrict__ Hs,            // (T*B) x 768 inverted bf16
    const __hip_bfloat16* __restrict__ Wp,   // 80 x H (padded bf16)
    const float* __restrict__ bpost,         // 72
    float* __restrict__ out)                 // B x T x 72
{
    const int mt = blockIdx.x;
    const int lane = threadIdx.x;
    const int col = lane & 15;
    const int quad = lane >> 4;

    const short* Ap = Hs + (size_t)(mt * 16 + col) * H + quad * 8;
    const short* Wb = (const short*)Wp;

    f32x4 acc[5];
#pragma unroll
    for (int nt = 0; nt < 5; ++nt) acc[nt] = (f32x4){0.f, 0.f, 0.f, 0.f};

    for (int k = 0; k < H; k += 32) {
        short8 a = ~(*(const short8*)(Ap + k));   // un-invert
#pragma unroll
        for (int nt = 0; nt < 5; ++nt) {
            short8 b = *(const short8*)(Wb + (size_t)(nt * 16 + col) * H + quad * 8 + k);
            acc[nt] = __builtin_amdgcn_mfma_f32_16x16x32_bf16(a, b, acc[nt], 0, 0, 0);
        }
    }

#pragma unroll
    for (int nt = 0; nt < 5; ++nt) {
        const int o = nt * 16 + col;
        if (o < 72) {
            const float bb = bpost[o];
#pragma unroll
            for (int r = 0; r < 4; ++r) {
                const int m = mt * 16 + quad * 4 + r;
                const int t = m >> 8;        // row = t*256 + b
                const int b = m & 255;
                out[((size_t)b * T + t) * 72 + o] = acc[nt][r] + bb;
            }
        }
    }
}

// ---------------- launch ----------------

extern "C" void kernel_launch(void* const* d_in, const int* in_sizes, int n_in,
                              void* d_out, int out_size, void* d_ws, size_t ws_size,
                              hipStream_t stream) {
    const float* src   = (const float*)d_in[0];
    const float* h0    = (const float*)d_in[2];
    const float* c0    = (const float*)d_in[3];
    const float* Wih   = (const float*)d_in[4];
    const float* Whh   = (const float*)d_in[5];
    const float* bih   = (const float*)d_in[6];
    const float* bhh   = (const float*)d_in[7];
    const float* Wpost = (const float*)d_in[8];
    const float* bpost = (const float*)d_in[9];
    float* out = (float*)d_out;

    char* ws = (char*)d_ws;
    __hip_bfloat16* Wcat = (__hip_bfloat16*)(ws + 0);          //  9,437,184 B
    __hip_bfloat16* Wc   = (__hip_bfloat16*)(ws + 9437184);    //  4,718,592 B
    float*          bias = (float*)(ws + 14155776);            //     12,288 B
    __hip_bfloat16* Wp   = (__hip_bfloat16*)(ws + 14168064);   //    122,880 B
    __hip_bfloat16* A0   = (__hip_bfloat16*)(ws + 14290944);   //    786,432 B
    unsigned*       sig  = (unsigned*)(ws + 15863808);         // 39,321,600 B

    // all prep (sig zero, weights, Wp, A0) in one vectorized dispatch
    prep_all<<<5808, 256, 0, stream>>>(src, h0, Wih, Whh, bih, bhh, Wpost,
                                       Wc, Wcat, bias, Wp, A0, (u64*)sig);

    // steps 0..99 in one persistent kernel (R14 protocol + R22 serial-path cuts)
    lstm_persist<<<256, 768, 0, stream>>>(Wc, Wcat, bias, c0, A0, sig);

    proj<<<1600, 64, 0, stream>>>((const short*)sig, Wp, bpost, out);
}

// Round 8
// 438.539 us; speedup vs baseline: 1.0468x; 1.0468x over previous
//
#include <hip/hip_runtime.h>
#include <hip/hip_bf16.h>
#include <math.h>

#define H 768
#define B 256
#define T 100

typedef __attribute__((ext_vector_type(8))) short short8;
typedef __attribute__((ext_vector_type(4))) float f32x4;
typedef __attribute__((ext_vector_type(4))) unsigned short us4;
typedef unsigned long long u64;

static __device__ __forceinline__ float sigm(float x) {
    return 1.0f / (1.0f + __expf(-x));
}
static __device__ __forceinline__ float tanh_fast(float x) {
    return 1.0f - 2.0f / (__expf(2.0f * x) + 1.0f);
}
static __device__ __forceinline__ unsigned short bf16b(float x) {
    __hip_bfloat16 h = __float2bfloat16(x);
    return *(unsigned short*)&h;
}

// ---------------- fused prep, R19 vectorized (single dispatch) ----------------
//   bid <  2400 : sig zero   (block: 16KB via 4 x 16B stores/thread)
//   bid <  5472 : weight row y=bid-2400 (tid<192: float4 x2 loads,
//                 us4 stores to Wc + Wcat; tid==0: bias)
//   bid <  5552 : Wp row r=bid-5472 (zero-padded beyond 72)
//   bid <  5808 : A0 batch row b=bid-5552  [x0|h0]
__global__ __launch_bounds__(256) void prep_all(
        const float* __restrict__ src, const float* __restrict__ h0,
        const float* __restrict__ Wih, const float* __restrict__ Whh,
        const float* __restrict__ bih, const float* __restrict__ bhh,
        const float* __restrict__ Wpost,
        __hip_bfloat16* __restrict__ Wc,    // 3072 x 768 (Wih+Whh)
        __hip_bfloat16* __restrict__ Wcat,  // 3072 x 1536 [Wih|Whh]
        float* __restrict__ bias,           // 3072
        __hip_bfloat16* __restrict__ Wp,    // 80 x 768
        __hip_bfloat16* __restrict__ A0,    // 256 x 1536 [x0|h0]
        u64* __restrict__ sig64)            // T*B*192 u64, zeroed
{
    const int bid = blockIdx.x;
    const int tid = threadIdx.x;

    if (bid < 2400) {
        char* bz = (char*)sig64 + (size_t)bid * 16384;
        const f32x4 z = {0.f, 0.f, 0.f, 0.f};
#pragma unroll
        for (int jj = 0; jj < 4; ++jj)
            *(f32x4*)(bz + (size_t)jj * 4096 + (size_t)tid * 16) = z;
    } else if (bid < 5472) {
        const int y = bid - 2400;
        if (tid < 192) {
            const int k4 = tid * 4;
            f32x4 a = *(const f32x4*)(Wih + (size_t)y * H + k4);
            f32x4 b = *(const f32x4*)(Whh + (size_t)y * H + k4);
            us4 wc, wa, wb;
#pragma unroll
            for (int i = 0; i < 4; ++i) {
                wc[i] = bf16b(a[i] + b[i]);
                wa[i] = bf16b(a[i]);
                wb[i] = bf16b(b[i]);
            }
            unsigned short* WcS   = (unsigned short*)Wc;
            unsigned short* WcatS = (unsigned short*)Wcat;
            *(us4*)(WcS   + (size_t)y * 768  + k4)       = wc;
            *(us4*)(WcatS + (size_t)y * 1536 + k4)       = wa;
            *(us4*)(WcatS + (size_t)y * 1536 + 768 + k4) = wb;
        }
        if (tid == 0) bias[y] = bih[y] + bhh[y];
    } else if (bid < 5552) {
        const int r = bid - 5472;
        if (tid < 192) {
            const int k4 = tid * 4;
            us4 w = {0, 0, 0, 0};
            if (r < 72) {
                f32x4 v = *(const f32x4*)(Wpost + (size_t)r * H + k4);
#pragma unroll
                for (int i = 0; i < 4; ++i) w[i] = bf16b(v[i]);
            }
            *(us4*)((unsigned short*)Wp + (size_t)r * 768 + k4) = w;
        }
    } else {
        const int b = bid - 5552;
        if (tid < 192) {
            const int k4 = tid * 4;
            f32x4 s = *(const f32x4*)(src + ((size_t)b * 16 + 15) * H + k4);
            f32x4 h = *(const f32x4*)(h0  + (size_t)b * H + k4);
            us4 ws, wh;
#pragma unroll
            for (int i = 0; i < 4; ++i) { ws[i] = bf16b(s[i]); wh[i] = bf16b(h[i]); }
            unsigned short* A0S = (unsigned short*)A0;
            *(us4*)(A0S + (size_t)b * 1536 + k4)       = ws;
            *(us4*)(A0S + (size_t)b * 1536 + 768 + k4) = wh;
        }
    }
}

// ---------------- persistent recurrence: steps 0..99 ----------------
// R14 core (proven 354us) with ONE R23 change: the poll retry loop has NO
// s_sleep. Model: step time is quantized to poll-sweep periods; a sweep =
// sleep(256cy) + batched-load MALL RT (~800cy) + body ~= 1.1us, and a step
// pays 2-3 sweeps (~3.5us measured). The load RT itself throttles the loop;
// barrier (D) still bounds each step's poll window (R13's flood came from
// removing (D), not the sleep).
// Refuted-by-counters (do not revisit): store-drain removal at (D) + dual
// accumulator MFMA chains (R22: both null, +3.6us); sc0/L2 exchange (R16);
// flag-gated exchange (R17); proj folded into tail (R18).
#define LDS_H_STRIDE  772    // shorts; 8B-aligned rows, low conflicts (R9-measured)
#define LDS_T0_STRIDE 1540   // shorts
#define XCH_STRIDE    17     // 16 + 1 pad floats

#define LDW8(n0,n1,n2,n3,n4,n5,n6,n7, p) \
    asm volatile("global_load_dwordx4 %0, %8, off\n\t" \
                 "global_load_dwordx4 %1, %8, off offset:64\n\t" \
                 "global_load_dwordx4 %2, %8, off offset:128\n\t" \
                 "global_load_dwordx4 %3, %8, off offset:192\n\t" \
                 "global_load_dwordx4 %4, %8, off offset:256\n\t" \
                 "global_load_dwordx4 %5, %8, off offset:320\n\t" \
                 "global_load_dwordx4 %6, %8, off offset:384\n\t" \
                 "global_load_dwordx4 %7, %8, off offset:448\n\t" \
                 "s_waitcnt vmcnt(0)" \
                 : "=&v"(n0),"=&v"(n1),"=&v"(n2),"=&v"(n3), \
                   "=&v"(n4),"=&v"(n5),"=&v"(n6),"=&v"(n7) \
                 : "v"(p))

#define KSTEP(nm, idx) { \
    short8 a_ = *(const short8*)(&lds_h[col * LDS_H_STRIDE + (idx) * 32 + quad * 8]); \
    acc = __builtin_amdgcn_mfma_f32_16x16x32_bf16(a_, nm, acc, 0, 0, 0); }

static __device__ __forceinline__ bool sig_ok(u64 x) {
    return (unsigned short)x && (unsigned short)(x >> 16) &&
           (unsigned short)(x >> 32) && (unsigned short)(x >> 48);
}

__global__ __launch_bounds__(768, 3) void lstm_persist(
    const __hip_bfloat16* __restrict__ Wc,    // 3072 x 768 bf16 (Wih+Whh)
    const __hip_bfloat16* __restrict__ Wcat,  // 3072 x 1536 bf16 [Wih|Whh]
    const float* __restrict__ bias,           // 3072
    const float* __restrict__ c0in,           // B x H fp32
    const __hip_bfloat16* __restrict__ A0,    // 256 x 1536 [x0|h0]
    unsigned* sig)                            // T x B x 384 u32 (~bf16 pairs), zeroed
{
    const int mtg  = blockIdx.x >> 4;    // batch group 0..15 (16 batches)
    const int jg   = blockIdx.x & 15;    // j group 0..15 (48 j values)
    const int tid  = threadIdx.x;
    const int lane = tid & 63;
    const int wave = tid >> 6;           // 0..11
    const int col  = lane & 15;
    const int quad = lane >> 4;
    const int jt_l = wave >> 2;          // 0..2  local j-tile
    const int gate = wave & 3;           // 0..3  (i,f,g,o)
    const int j    = jg * 48 + jt_l * 16 + col;   // this wave's j column

    __shared__ short lds_h[16 * LDS_T0_STRIDE];   // 49280 B (t0 tile; t>=1 stride 772)
    __shared__ float xch[12 * 16 * XCH_STRIDE];   // 13056 B gate exchange

    // ---- pin resident weight slice (Wc) in regs: 24 x short8 (sound asm) ----
    const short* wptr = (const short*)Wc + (size_t)(gate * H + j) * H + quad * 8;
    short8 w00,w01,w02,w03,w04,w05,w06,w07,w08,w09,w10,w11,
           w12,w13,w14,w15,w16,w17,w18,w19,w20,w21,w22,w23;
    LDW8(w00,w01,w02,w03,w04,w05,w06,w07, wptr);
    LDW8(w08,w09,w10,w11,w12,w13,w14,w15, wptr + 256);
    LDW8(w16,w17,w18,w19,w20,w21,w22,w23, wptr + 512);

    // ---- cell-role state (threads 0..383: two adjacent-j cells each) ----
    const int p    = tid;                 // pair id if < 384 (waves 0..5)
    const int bb   = p / 24;              // local batch 0..15
    const int jp   = p % 24;
    const int jloc = jp * 2;              // local j 0..46 (even)
    const int cjt  = jloc >> 4;           // j-tile of the pair
    const int jcol = jloc & 15;
    const int bglob = mtg * 16 + bb;
    const int jglob = jg * 48 + jloc;
    float c0v = 0.f, c1v = 0.f;
    float bi0=0,bi1=0,bf0=0,bf1=0,bg0=0,bg1=0,bo0=0,bo1=0;
    if (p < 384) {
        c0v = c0in[(size_t)bglob * H + jglob];
        c1v = c0in[(size_t)bglob * H + jglob + 1];
        bi0 = bias[0*H + jglob]; bi1 = bias[0*H + jglob + 1];
        bf0 = bias[1*H + jglob]; bf1 = bias[1*H + jglob + 1];
        bg0 = bias[2*H + jglob]; bg1 = bias[2*H + jglob + 1];
        bo0 = bias[3*H + jglob]; bo1 = bias[3*H + jglob + 1];
    }

    const u64* sig64c = (const u64*)sig;
    const int r0  = tid / 192;    // staging row base 0..3
    const int wrd = tid % 192;    // u64 word within row

    for (int t = 0; t < T; ++t) {
        f32x4 acc = {0.f, 0.f, 0.f, 0.f};

        if (t == 0) {
            // ---- stage A0[16 rows][1536] -> LDS (plain loads) ----
            const u64* a8 = (const u64*)((const short*)A0 + (size_t)(mtg * 16) * 1536);
#pragma unroll
            for (int i = 0; i < 8; ++i) {
                int idx = tid + i * 768;      // 0..6143 (16 rows x 384 u64)
                int br  = idx / 384;
                int ch  = idx % 384;
                *(u64*)&lds_h[br * LDS_T0_STRIDE + ch * 4] = a8[(size_t)br * 384 + ch];
            }
            __syncthreads();   // (B)

            // ---- K=1536 GEMM streaming Wcat (one-time) ----
            const short* wq = (const short*)Wcat + (size_t)(gate * H + j) * 1536 + quad * 8;
            for (int kk = 0; kk < 48; ++kk) {
                short8 a_ = *(const short8*)(&lds_h[col * LDS_T0_STRIDE + kk * 32 + quad * 8]);
                short8 b_ = *(const short8*)(wq + kk * 32);
                acc = __builtin_amdgcn_mfma_f32_16x16x32_bf16(a_, b_, acc, 0, 0, 0);
            }
        } else {
            // ---- poll+stage h(t-1): 4 owned u64 words, BATCHED loads.
            //      R23: NO sleep in the retry loop — the batched load's MALL
            //      round trip (~800cy) is the throttle; (D) bounds the window.
            const u64* hb = sig64c + ((size_t)(t - 1) * B + (size_t)(mtg * 16)) * 192 + wrd;
            u64 x0 = __hip_atomic_load(hb + (size_t)(r0     ) * 192,
                                       __ATOMIC_RELAXED, __HIP_MEMORY_SCOPE_AGENT);
            u64 x1 = __hip_atomic_load(hb + (size_t)(r0 +  4) * 192,
                                       __ATOMIC_RELAXED, __HIP_MEMORY_SCOPE_AGENT);
            u64 x2 = __hip_atomic_load(hb + (size_t)(r0 +  8) * 192,
                                       __ATOMIC_RELAXED, __HIP_MEMORY_SCOPE_AGENT);
            u64 x3 = __hip_atomic_load(hb + (size_t)(r0 + 12) * 192,
                                       __ATOMIC_RELAXED, __HIP_MEMORY_SCOPE_AGENT);
            unsigned pending = 0xFu;
            if (sig_ok(x0)) { *(u64*)&lds_h[(r0     ) * LDS_H_STRIDE + wrd * 4] = ~x0; pending &= ~1u; }
            if (sig_ok(x1)) { *(u64*)&lds_h[(r0 +  4) * LDS_H_STRIDE + wrd * 4] = ~x1; pending &= ~2u; }
            if (sig_ok(x2)) { *(u64*)&lds_h[(r0 +  8) * LDS_H_STRIDE + wrd * 4] = ~x2; pending &= ~4u; }
            if (sig_ok(x3)) { *(u64*)&lds_h[(r0 + 12) * LDS_H_STRIDE + wrd * 4] = ~x3; pending &= ~8u; }
            int guard = 0;
            while (pending && ++guard < (1 << 22)) {
                if (pending & 1u) x0 = __hip_atomic_load(hb + (size_t)(r0     ) * 192,
                                        __ATOMIC_RELAXED, __HIP_MEMORY_SCOPE_AGENT);
                if (pending & 2u) x1 = __hip_atomic_load(hb + (size_t)(r0 +  4) * 192,
                                        __ATOMIC_RELAXED, __HIP_MEMORY_SCOPE_AGENT);
                if (pending & 4u) x2 = __hip_atomic_load(hb + (size_t)(r0 +  8) * 192,
                                        __ATOMIC_RELAXED, __HIP_MEMORY_SCOPE_AGENT);
                if (pending & 8u) x3 = __hip_atomic_load(hb + (size_t)(r0 + 12) * 192,
                                        __ATOMIC_RELAXED, __HIP_MEMORY_SCOPE_AGENT);
                if ((pending & 1u) && sig_ok(x0)) { *(u64*)&lds_h[(r0     ) * LDS_H_STRIDE + wrd * 4] = ~x0; pending &= ~1u; }
                if ((pending & 2u) && sig_ok(x1)) { *(u64*)&lds_h[(r0 +  4) * LDS_H_STRIDE + wrd * 4] = ~x1; pending &= ~2u; }
                if ((pending & 4u) && sig_ok(x2)) { *(u64*)&lds_h[(r0 +  8) * LDS_H_STRIDE + wrd * 4] = ~x2; pending &= ~4u; }
                if ((pending & 8u) && sig_ok(x3)) { *(u64*)&lds_h[(r0 + 12) * LDS_H_STRIDE + wrd * 4] = ~x3; pending &= ~8u; }
            }
            __syncthreads();   // (B) lds_h ready

            // ---- K=768 GEMM vs pinned weights ----
            KSTEP(w00,0)  KSTEP(w01,1)  KSTEP(w02,2)  KSTEP(w03,3)
            KSTEP(w04,4)  KSTEP(w05,5)  KSTEP(w06,6)  KSTEP(w07,7)
            KSTEP(w08,8)  KSTEP(w09,9)  KSTEP(w10,10) KSTEP(w11,11)
            KSTEP(w12,12) KSTEP(w13,13) KSTEP(w14,14) KSTEP(w15,15)
            KSTEP(w16,16) KSTEP(w17,17) KSTEP(w18,18) KSTEP(w19,19)
            KSTEP(w20,20) KSTEP(w21,21) KSTEP(w22,22) KSTEP(w23,23)
        }

        // ---- exchange gate tiles through LDS ----
        float* xw = &xch[(size_t)wave * 16 * XCH_STRIDE];
#pragma unroll
        for (int r = 0; r < 4; ++r)
            xw[(quad * 4 + r) * XCH_STRIDE + col] = acc[r];
        __syncthreads();   // (C) xch ready; all lds_h reads of this step done

        // ---- cell update + inverted-bf16 publish (store IS the signal) ----
        if (p < 384) {
            const float* xg = &xch[(size_t)(cjt * 4) * 16 * XCH_STRIDE + bb * XCH_STRIDE + jcol];
            const int gs = 16 * XCH_STRIDE;
            float i0 = xg[0*gs] + bi0, i1 = xg[0*gs + 1] + bi1;
            float f0 = xg[1*gs] + bf0, f1 = xg[1*gs + 1] + bf1;
            float g0 = xg[2*gs] + bg0, g1 = xg[2*gs + 1] + bg1;
            float o0 = xg[3*gs] + bo0, o1 = xg[3*gs + 1] + bo1;
            float cn0 = sigm(f0) * c0v + sigm(i0) * tanh_fast(g0);
            float cn1 = sigm(f1) * c1v + sigm(i1) * tanh_fast(g1);
            c0v = cn0; c1v = cn1;
            __hip_bfloat16 h0b = __float2bfloat16(sigm(o0) * tanh_fast(cn0));
            __hip_bfloat16 h1b = __float2bfloat16(sigm(o1) * tanh_fast(cn1));
            unsigned lo = (unsigned)(unsigned short)~(*(unsigned short*)&h0b);  // nonzero
            unsigned hi = (unsigned)(unsigned short)~(*(unsigned short*)&h1b);  // nonzero
            __hip_atomic_store(&sig[((size_t)t * B + bglob) * 384 + (jglob >> 1)],
                               lo | (hi << 16),
                               __ATOMIC_RELAXED, __HIP_MEMORY_SCOPE_AGENT);
        }
        __syncthreads();   // (D) poll throttle: park all waves until publish done
    }
}

// ---------------- post projection (reads inverted sig) ----------------
__global__ __launch_bounds__(64) void proj(
    const short* __restrict__ Hs,            // (T*B) x 768 inverted bf16
    const __hip_bfloat16* __restrict__ Wp,   // 80 x H (padded bf16)
    const float* __restrict__ bpost,         // 72
    float* __restrict__ out)                 // B x T x 72
{
    const int mt = blockIdx.x;
    const int lane = threadIdx.x;
    const int col = lane & 15;
    const int quad = lane >> 4;

    const short* Ap = Hs + (size_t)(mt * 16 + col) * H + quad * 8;
    const short* Wb = (const short*)Wp;

    f32x4 acc[5];
#pragma unroll
    for (int nt = 0; nt < 5; ++nt) acc[nt] = (f32x4){0.f, 0.f, 0.f, 0.f};

    for (int k = 0; k < H; k += 32) {
        short8 a = ~(*(const short8*)(Ap + k));   // un-invert
#pragma unroll
        for (int nt = 0; nt < 5; ++nt) {
            short8 b = *(const short8*)(Wb + (size_t)(nt * 16 + col) * H + quad * 8 + k);
            acc[nt] = __builtin_amdgcn_mfma_f32_16x16x32_bf16(a, b, acc[nt], 0, 0, 0);
        }
    }

#pragma unroll
    for (int nt = 0; nt < 5; ++nt) {
        const int o = nt * 16 + col;
        if (o < 72) {
            const float bb = bpost[o];
#pragma unroll
            for (int r = 0; r < 4; ++r) {
                const int m = mt * 16 + quad * 4 + r;
                const int t = m >> 8;        // row = t*256 + b
                const int b = m & 255;
                out[((size_t)b * T + t) * 72 + o] = acc[nt][r] + bb;
            }
        }
    }
}

// ---------------- launch ----------------

extern "C" void kernel_launch(void* const* d_in, const int* in_sizes, int n_in,
                              void* d_out, int out_size, void* d_ws, size_t ws_size,
                              hipStream_t stream) {
    const float* src   = (const float*)d_in[0];
    const float* h0    = (const float*)d_in[2];
    const float* c0    = (const float*)d_in[3];
    const float* Wih   = (const float*)d_in[4];
    const float* Whh   = (const float*)d_in[5];
    const float* bih   = (const float*)d_in[6];
    const float* bhh   = (const float*)d_in[7];
    const float* Wpost = (const float*)d_in[8];
    const float* bpost = (const float*)d_in[9];
    float* out = (float*)d_out;

    char* ws = (char*)d_ws;
    __hip_bfloat16* Wcat = (__hip_bfloat16*)(ws + 0);          //  9,437,184 B
    __hip_bfloat16* Wc   = (__hip_bfloat16*)(ws + 9437184);    //  4,718,592 B
    float*          bias = (float*)(ws + 14155776);            //     12,288 B
    __hip_bfloat16* Wp   = (__hip_bfloat16*)(ws + 14168064);   //    122,880 B
    __hip_bfloat16* A0   = (__hip_bfloat16*)(ws + 14290944);   //    786,432 B
    unsigned*       sig  = (unsigned*)(ws + 15863808);         // 39,321,600 B

    // all prep (sig zero, weights, Wp, A0) in one vectorized dispatch
    prep_all<<<5808, 256, 0, stream>>>(src, h0, Wih, Whh, bih, bhh, Wpost,
                                       Wc, Wcat, bias, Wp, A0, (u64*)sig);

    // steps 0..99 in one persistent kernel (R14 core + R23 sleepless retry)
    lstm_persist<<<256, 768, 0, stream>>>(Wc, Wcat, bias, c0, A0, sig);

    proj<<<1600, 64, 0, stream>>>((const short*)sig, Wp, bpost, out);
}